// Round 6
// baseline (16008.994 us; speedup 1.0000x reference)
//
#include <hip/hip_runtime.h>

// ---------------------------------------------------------------------------
// PolicyNetRSNNPB forward, MI355X/gfx950.  Round 6: numpy-float32 EMULATION.
//
// Evidence chain: r1/r2/r5 (three disjoint exact pipelines) bit-identical
// absmax 0.3251953125 = 333/1024 => exact-math trajectory != reference;
// reference is numpy float32 (BLAS sgemm). This round reproduces np-fp32
// bit-exactly:
//   * GEMMs: per-element single-accumulator sequential-k FMA (BLAS x86
//     microkernel semantics), K=512 split at OpenBLAS SGEMM_Q=384:
//     G = R(seqFMA[0..384) + seqFMA[384..512)).  K=128/K=64: pure seq.
//   * Elementwise in Python expression order, single-rounded ops, no FMA
//     contraction (__fmul_rn/__fadd_rn/__fsub_rn).
//   * All state fp32. Spikes exact {0,1}; exchange protocol from r5.
//  K1 k_xw  : XW = R(seqFMA(x@Win^T) + b_in)            [fp32]
//  K2 k_rec : 512-step recurrence, fp32 faithful         [VALU]
//  K3 k_c3  : c3 = R(G_512(spk_f, Wmu/lv) + b)           [fp32 VALU]
//  K4 k_scan: mem = R(R(beta*mem) + c3), store all t'    [fp32]
//  K5 k_out : mu = seqFMA_64(mem,Wout); out=R(mu0+mu1)*0.5
// ---------------------------------------------------------------------------

typedef unsigned int       u32;
typedef unsigned short     u16;
typedef unsigned long long u64;
typedef unsigned char      u8;

#define TSTEPS 512
#define HIDDEN 512

// workspace layout (bytes) — WS_NEED identical to r0/r5 (proven available).
#define XW_OFF    0ull           // fp32 32768*512*4 = 67108864 (dead after K2)
#define C3_OFF    0ull           // fp32 65536*128*4 = 33554432 (alias XW)
#define MEM_OFF   33554432ull    // fp32 65536*128*4 = 33554432 (alias XW)
#define SPKF_OFF  100663296ull   // u8   512*128*512 = 33554432
#define RINGF_OFF 134217728ull   // fp32 2*128*512*4 = 524288
#define CNT_OFF   134742016ull   // 4096
#define WS_NEED   (134742016ull + 4096ull)

#define QCHUNK 384   // OpenBLAS SGEMM_DEFAULT_Q (Haswell/Zen)

// ---------------------------------------------------------------------------
// K1: XW[row,j] = R(seqFMA_{k=0..127}(x[row,k]*Win[j,k]) + b_in[j]).
// grid 2048 (16 rows each), block 256 (thread = column j, two halves).
// ---------------------------------------------------------------------------
__global__ __launch_bounds__(256) void k_xw(
    const float* __restrict__ state, const float* __restrict__ target,
    const float* __restrict__ Win, const float* __restrict__ b_in,
    float* __restrict__ XW)
{
  __shared__ float xs[16][129];
  const int tid  = threadIdx.x;
  const int row0 = blockIdx.x * 16;

  for (int e = tid; e < 2048; e += 256) {
    int r = e >> 7, k = e & 127;
    xs[r][k] = (k < 64) ? state[(row0 + r) * 64 + k]
                        : target[(row0 + r) * 64 + k - 64];
  }
  __syncthreads();

#pragma unroll
  for (int jh = 0; jh < 2; ++jh) {
    const int j = jh * 256 + tid;
    float acc[16];
#pragma unroll
    for (int r = 0; r < 16; ++r) acc[r] = 0.0f;
    const float* wrow = Win + j * 128;
    for (int k = 0; k < 128; ++k) {          // strictly ascending k
      const float wv = wrow[k];
#pragma unroll
      for (int r = 0; r < 16; ++r)
        acc[r] = __builtin_fmaf(xs[r][k], wv, acc[r]);
    }
    const float b = b_in[j];
#pragma unroll
    for (int r = 0; r < 16; ++r)
      XW[(row0 + r) * 512 + j] = __fadd_rn(acc[r], b);
  }
}

// ---------------------------------------------------------------------------
// K2: fp32-faithful recurrence. grid 64 = 8 groups (batch) x 8 members
// (channel slices), block 256, 1 WG/CU (LDS 140 KB). Thread owns channel jj
// and 4 batch rows. Rec GEMM from LDS-resident W_rec slice; ff GEMM streamed
// from L2. Sequential-k FMA with the 384-chunk merge.
// ---------------------------------------------------------------------------
__global__ __launch_bounds__(256, 1) void k_rec(
    const float* __restrict__ XW,
    const float* __restrict__ Wrec, const float* __restrict__ Wff,
    const float* __restrict__ alpha_rec, const float* __restrict__ beta_rec,
    const float* __restrict__ b_rec,
    const float* __restrict__ b_ff, const float* __restrict__ alpha_ff,
    const float* __restrict__ beta_ff,
    float* __restrict__ ringf, u8* __restrict__ spkf, u32* __restrict__ cnt)
{
  __shared__ float Wl[64 * 516];     // 132096 B: W_rec slice
  __shared__ u8    AsT[512 * 16];    // 8192 B: spikes transposed [k][m]

  const int tid  = threadIdx.x;
  const int g    = blockIdx.x & 7;
  const int c    = blockIdx.x >> 3;
  const int n0   = g * 16;
  const int lane = tid & 63;
  const int w    = tid >> 6;
  const int l15  = lane & 15;
  const int quad = lane >> 4;
  const int jl   = w * 16 + l15;
  const int jj   = c * 64 + jl;

  for (int it = tid; it < 8192; it += 256) {
    const int row = it >> 7, k4 = (it & 127) * 4;
    float4 v = *(const float4*)(Wrec + (c * 64 + row) * 512 + k4);
    *(float4*)(Wl + row * 516 + k4) = v;
  }

  const float* wffrow = Wff + jj * 512;

  const float ars = alpha_rec[jj], brs = beta_rec[jj];
  const float afs = alpha_ff[jj],  bfs = beta_ff[jj];
  const float brecs = b_rec[jj],   bffs = b_ff[jj];

  float synR[4] = {0,0,0,0}, memR[4] = {0,0,0,0};
  float synF[4] = {0,0,0,0}, memF[4] = {0,0,0,0};
  float spkR[4] = {0,0,0,0}, spkF[4] = {0,0,0,0};

  const int sn  = tid & 15;
  const int seg = tid >> 4;
  u32* cg = cnt + g * 32;

  __syncthreads();  // Wl ready

  for (int tp = 0; tp <= TSTEPS; ++tp) {
    float xw[4] = {0,0,0,0};
    if (tp < TSTEPS) {
      const float* ph = XW + ((tp >> 1) * 128 + n0 + quad * 4) * 512 + jj;
#pragma unroll
      for (int r = 0; r < 4; ++r) xw[r] = ph[r * 512];
    }

    float SR[4] = {0,0,0,0}, SF[4] = {0,0,0,0};

    if (tp > 0) {
      if (tid == 0) {
        const u32 tgt = 8u * (u32)tp;
        while (__hip_atomic_load(cg, __ATOMIC_ACQUIRE, __HIP_MEMORY_SCOPE_AGENT) < tgt)
          __builtin_amdgcn_s_sleep(1);
      }
      __syncthreads();

      { // stage spk_r[tp-1] -> transposed bytes AsT[k][m]
        const float* src = ringf + (((tp & 1) ^ 1) * 128 + n0 + sn) * 512 + seg * 32;
#pragma unroll
        for (int u = 0; u < 32; ++u) {
          float v = __hip_atomic_load(src + u, __ATOMIC_RELAXED, __HIP_MEMORY_SCOPE_AGENT);
          AsT[(seg * 32 + u) * 16 + sn] = (v != 0.f) ? (u8)1 : (u8)0;
        }
      }
      __syncthreads();

      // BLAS-faithful fp32 GEMMs: seq-FMA, chunk boundary at k=384
      float aRA[4] = {0,0,0,0}, aRB[4] = {0,0,0,0};
      float aFA[4] = {0,0,0,0}, aFB[4] = {0,0,0,0};
#pragma unroll 4
      for (int k = 0; k < QCHUNK; ++k) {
        const u32 sb = *(const u32*)(AsT + k * 16 + quad * 4);
        const float wr = Wl[jl * 516 + k];
        const float wf = wffrow[k];
#pragma unroll
        for (int r = 0; r < 4; ++r) {
          const float b = (float)((sb >> (8 * r)) & 1u);
          aRA[r] = __builtin_fmaf(b, wr, aRA[r]);
          aFA[r] = __builtin_fmaf(b, wf, aFA[r]);
        }
      }
#pragma unroll 4
      for (int k = QCHUNK; k < 512; ++k) {
        const u32 sb = *(const u32*)(AsT + k * 16 + quad * 4);
        const float wr = Wl[jl * 516 + k];
        const float wf = wffrow[k];
#pragma unroll
        for (int r = 0; r < 4; ++r) {
          const float b = (float)((sb >> (8 * r)) & 1u);
          aRB[r] = __builtin_fmaf(b, wr, aRB[r]);
          aFB[r] = __builtin_fmaf(b, wf, aFB[r]);
        }
      }
#pragma unroll
      for (int r = 0; r < 4; ++r) {
        SR[r] = __fadd_rn(aRA[r], aRB[r]);
        SF[r] = __fadd_rn(aFA[r], aFB[r]);
      }

      // ff epilogue for step tp-1 (np expression order, single-rounded)
#pragma unroll
      for (int r = 0; r < 4; ++r) {
        float curf = __fadd_rn(SF[r], bffs);
        synF[r] = __fadd_rn(__fmul_rn(afs, synF[r]), curf);
        memF[r] = __fsub_rn(__fadd_rn(__fmul_rn(bfs, memF[r]), synF[r]), spkF[r]);
        spkF[r] = (memF[r] > 1.0f) ? 1.0f : 0.0f;
        const int m = quad * 4 + r;
        spkf[((u64)(tp - 1) * 128 + n0 + m) * 512 + jj] = (u8)(spkF[r] != 0.f);
      }
    }

    if (tp < TSTEPS) {
      // rec epilogue for step tp
#pragma unroll
      for (int r = 0; r < 4; ++r) {
        float cur = __fadd_rn(__fadd_rn(xw[r], SR[r]), brecs);
        synR[r] = __fadd_rn(__fmul_rn(ars, synR[r]), cur);
        memR[r] = __fsub_rn(__fadd_rn(__fmul_rn(brs, memR[r]), synR[r]), spkR[r]);
        spkR[r] = (memR[r] > 1.0f) ? 1.0f : 0.0f;
        const int m = quad * 4 + r;
        __hip_atomic_store(ringf + ((tp & 1) * 128 + n0 + m) * 512 + jj, spkR[r],
                           __ATOMIC_RELAXED, __HIP_MEMORY_SCOPE_AGENT);
      }
    }
    __syncthreads();   // compiler drains vmcnt before barrier

    if (tp < TSTEPS && tid == 0)
      __hip_atomic_fetch_add(cg, 1u, __ATOMIC_RELEASE, __HIP_MEMORY_SCOPE_AGENT);
  }
}

// ---------------------------------------------------------------------------
// K3: c3[row,j] = R(G + bias), G = R(seqFMA[0,384) + seqFMA[384,512)) of
// spk_f[row,:] * W[j,:].  grid 1024 (64 rows), block 256: thread=(rh,j).
// ---------------------------------------------------------------------------
__global__ __launch_bounds__(256) void k_c3(
    const u8* __restrict__ spkf,
    const float* __restrict__ Wmu, const float* __restrict__ bmu,
    const float* __restrict__ Wlv, const float* __restrict__ blv,
    float* __restrict__ c3)
{
  __shared__ u8 As[64 * 512];   // 32768 B
  const int tid  = threadIdx.x;
  const int row0 = blockIdx.x * 64;

  for (int it = tid; it < 2048; it += 256)
    *(uint4*)(As + it * 16) = *(const uint4*)(spkf + (u64)row0 * 512 + it * 16);
  __syncthreads();

  const int j  = tid & 127;
  const int rh = tid >> 7;
  const float* wrow = (j < 64) ? (Wmu + j * 512) : (Wlv + (j - 64) * 512);
  const float bias  = (j < 64) ? bmu[j] : blv[j - 64];

  for (int rr = 0; rr < 32; ++rr) {
    const int row = rh * 32 + rr;
    const u8* arow = As + row * 512;
    float accA = 0.0f, accB = 0.0f;
#pragma unroll 4
    for (int k = 0; k < QCHUNK; ++k)
      accA = __builtin_fmaf((float)arow[k], wrow[k], accA);
#pragma unroll 4
    for (int k = QCHUNK; k < 512; ++k)
      accB = __builtin_fmaf((float)arow[k], wrow[k], accB);
    c3[(u64)(row0 + row) * 128 + j] = __fadd_rn(__fadd_rn(accA, accB), bias);
  }
}

// ---------------------------------------------------------------------------
// K4: mem[t'] = R(R(beta*mem) + c3[t']), store every t'.  16384 threads.
// ---------------------------------------------------------------------------
__global__ __launch_bounds__(256) void k_scan(
    const float* __restrict__ c3,
    const float* __restrict__ beta_mu, const float* __restrict__ beta_lv,
    float* __restrict__ Mem)
{
  const int tid = blockIdx.x * 256 + threadIdx.x;
  const int n = tid >> 7, ap = tid & 127;
  const float beta = (ap < 64) ? beta_mu[ap] : beta_lv[ap - 64];
  const float* src = c3 + n * 128 + ap;
  float* dst = Mem + n * 128 + ap;
  float mem = 0.0f;
  for (int t = 0; t < 512; ++t) {
    mem = __fadd_rn(__fmul_rn(beta, mem), src[(u64)t * 16384]);
    dst[(u64)t * 16384] = mem;
  }
}

// ---------------------------------------------------------------------------
// K5: out[kind][t][n][a] = R(mu0+mu1)*0.5, mu = seqFMA_{q<64}(mem*Wout[a,q]).
// ---------------------------------------------------------------------------
__global__ __launch_bounds__(256) void k_out(
    const float* __restrict__ Mem,
    const float* __restrict__ Wmu_out, const float* __restrict__ Wlv_out,
    float* __restrict__ out)
{
  const int tid = blockIdx.x * 256 + threadIdx.x;
  const int a = tid & 7;
  const int n = (tid >> 3) & 127;
  const int t = (tid >> 10) & 255;
  const int kind = tid >> 18;
  const float* wv = ((kind == 0) ? Wmu_out : Wlv_out) + a * 64;
  const float* s0 = Mem + ((u64)(2 * t) * 128 + n) * 128 + kind * 64;
  const float* s1 = Mem + ((u64)(2 * t + 1) * 128 + n) * 128 + kind * 64;
  float mu0 = 0.0f, mu1 = 0.0f;
#pragma unroll 8
  for (int q = 0; q < 64; ++q) mu0 = __builtin_fmaf(s0[q], wv[q], mu0);
#pragma unroll 8
  for (int q = 0; q < 64; ++q) mu1 = __builtin_fmaf(s1[q], wv[q], mu1);
  out[tid] = __fmul_rn(__fadd_rn(mu0, mu1), 0.5f);
}

// ---------------------------------------------------------------------------
extern "C" void kernel_launch(void* const* d_in, const int* in_sizes, int n_in,
                              void* d_out, int out_size, void* d_ws, size_t ws_size,
                              hipStream_t stream) {
  (void)in_sizes; (void)n_in; (void)out_size;
  if (ws_size < WS_NEED) return;

  const float* state     = (const float*)d_in[0];
  const float* target    = (const float*)d_in[1];
  const float* W_rec_in  = (const float*)d_in[2];
  const float* b_rec_in  = (const float*)d_in[3];
  const float* W_rec     = (const float*)d_in[4];
  const float* b_rec     = (const float*)d_in[5];
  const float* alpha_rec = (const float*)d_in[6];
  const float* beta_rec  = (const float*)d_in[7];
  const float* W_ff_in   = (const float*)d_in[8];
  const float* b_ff_in   = (const float*)d_in[9];
  const float* alpha_ff  = (const float*)d_in[10];
  const float* beta_ff   = (const float*)d_in[11];
  const float* W_mu_in   = (const float*)d_in[12];
  const float* b_mu_in   = (const float*)d_in[13];
  const float* beta_mu   = (const float*)d_in[14];
  const float* W_mu_out  = (const float*)d_in[15];
  const float* W_lv_in   = (const float*)d_in[16];
  const float* b_lv_in   = (const float*)d_in[17];
  const float* beta_lv   = (const float*)d_in[18];
  const float* W_lv_out  = (const float*)d_in[19];

  char* ws = (char*)d_ws;
  float* XW   = (float*)(ws + XW_OFF);
  float* c3   = (float*)(ws + C3_OFF);
  float* Mem  = (float*)(ws + MEM_OFF);
  u8*    spkf = (u8*)   (ws + SPKF_OFF);
  float* ringf= (float*)(ws + RINGF_OFF);
  u32*   cnt  = (u32*)  (ws + CNT_OFF);

  hipMemsetAsync(cnt, 0, 4096, stream);

  hipLaunchKernelGGL(k_xw, dim3(2048), dim3(256), 0, stream,
                     state, target, W_rec_in, b_rec_in, XW);
  hipLaunchKernelGGL(k_rec, dim3(64), dim3(256), 0, stream,
                     XW, W_rec, W_ff_in,
                     alpha_rec, beta_rec, b_rec,
                     b_ff_in, alpha_ff, beta_ff, ringf, spkf, cnt);
  hipLaunchKernelGGL(k_c3, dim3(1024), dim3(256), 0, stream,
                     spkf, W_mu_in, b_mu_in, W_lv_in, b_lv_in, c3);
  hipLaunchKernelGGL(k_scan, dim3(64), dim3(256), 0, stream,
                     c3, beta_mu, beta_lv, Mem);
  hipLaunchKernelGGL(k_out, dim3(2048), dim3(256), 0, stream,
                     Mem, W_mu_out, W_lv_out, (float*)d_out);
}

// Round 7
// 8402.844 us; speedup vs baseline: 1.9052x; 1.9052x over previous
//
#include <hip/hip_runtime.h>

// ---------------------------------------------------------------------------
// PolicyNetRSNNPB forward, MI355X/gfx950.  Round 7: optimize r6 (passed,
// 16.0 ms) while preserving numpy-fp32 arithmetic BIT-EXACTLY:
//   * every GEMM accumulator: sequential-k FMA ascending, K=512 split into
//     [0,384)+[384,512) merged by one fadd (OpenBLAS SGEMM_Q=384 model);
//   * elementwise single-rounded, no contraction (__fmul_rn/__fadd_rn/...).
// Changes vs r6 (all order-preserving):
//  k_rec : 8 groups x 32 members (grid 256 = all CUs), 16 ch/member.
//          W_rec+W_ff slices LDS-resident; spikes exchanged as u32 bitmasks
//          (ballot-packed, 1 store/row/member; 2 coalesced loads/thread);
//          bits expanded in-register (bfe+cvt) -> float 0/1 FMA.
//  k_c3  : bitmask spikes + transposed weights (coalesced), k-outer.
//  k_xw  : transposed WinT (coalesced weight stream).
//  k_prepT: builds WinT and WT (mu|lv) transposes.
//  k_scan, k_out: unchanged from r6.
// ---------------------------------------------------------------------------

typedef unsigned int       u32;
typedef unsigned short     u16;
typedef unsigned long long u64;
typedef unsigned char      u8;

#define TSTEPS 512
#define HIDDEN 512

// workspace layout (bytes) — WS_NEED identical to r6 (proven available).
#define XW_OFF    0ull           // fp32 32768*512*4 = 67108864 (dead after k_rec)
#define C3_OFF    0ull           // fp32 65536*128*4 = 33554432 (alias XW)
#define MEM_OFF   33554432ull    // fp32 65536*128*4 = 33554432 (alias XW)
#define SPKB_OFF  100663296ull   // u32  512*128*32*4 = 8388608
#define WT_OFF    109051904ull   // fp32 512*128*4 = 262144  (mu|lv transposed)
#define WINT_OFF  109314048ull   // fp32 128*512*4 = 262144  (Win transposed)
#define RING_OFF  134217728ull   // u32  2*128*32*4 = 32768
#define CNT_OFF   134742016ull   // 4096
#define WS_NEED   (134742016ull + 4096ull)

#define QCHUNK 384   // OpenBLAS SGEMM_DEFAULT_Q

// ---------------------------------------------------------------------------
// k_prepT: WinT[k*512+j] = Win[j*128+k];  WT[k*128+j] = (Wmu|Wlv)[j][k].
// ---------------------------------------------------------------------------
__global__ __launch_bounds__(256) void k_prepT(
    const float* __restrict__ Win,
    const float* __restrict__ Wmu, const float* __restrict__ Wlv,
    float* __restrict__ WinT, float* __restrict__ WT)
{
  const int idx = blockIdx.x * 256 + threadIdx.x;   // 131072 threads
  if (idx < 65536) {
    const int k = idx >> 9, j = idx & 511;
    WinT[idx] = Win[j * 128 + k];
  } else {
    const int i2 = idx - 65536;
    const int k = i2 >> 7, j = i2 & 127;
    WT[i2] = (j < 64) ? Wmu[j * 512 + k] : Wlv[(j - 64) * 512 + k];
  }
}

// ---------------------------------------------------------------------------
// k_xw: XW[row,j] = R(seqFMA_{k<128}(x[row,k]*Win[j,k]) + b_in[j]).
// Same arithmetic as r6; weight stream now coalesced via WinT.
// grid 2048 (16 rows), block 256 (thread = column j, two halves).
// ---------------------------------------------------------------------------
__global__ __launch_bounds__(256) void k_xw(
    const float* __restrict__ state, const float* __restrict__ target,
    const float* __restrict__ WinT, const float* __restrict__ b_in,
    float* __restrict__ XW)
{
  __shared__ float xs[16][129];
  const int tid  = threadIdx.x;
  const int row0 = blockIdx.x * 16;

  for (int e = tid; e < 2048; e += 256) {
    int r = e >> 7, k = e & 127;
    xs[r][k] = (k < 64) ? state[(row0 + r) * 64 + k]
                        : target[(row0 + r) * 64 + k - 64];
  }
  __syncthreads();

#pragma unroll
  for (int jh = 0; jh < 2; ++jh) {
    const int j = jh * 256 + tid;
    float acc[16];
#pragma unroll
    for (int r = 0; r < 16; ++r) acc[r] = 0.0f;
    for (int k = 0; k < 128; ++k) {          // strictly ascending k
      const float wv = WinT[k * 512 + j];    // coalesced
#pragma unroll
      for (int r = 0; r < 16; ++r)
        acc[r] = __builtin_fmaf(xs[r][k], wv, acc[r]);
    }
    const float b = b_in[j];
#pragma unroll
    for (int r = 0; r < 16; ++r)
      XW[(row0 + r) * 512 + j] = __fadd_rn(acc[r], b);
  }
}

// ---------------------------------------------------------------------------
// k_rec: fp32-faithful recurrence. grid 256 = 8 groups (16 batch rows) x
// 32 members (16 channels), block 256 (thread = (jl 0..15, row 0..15)),
// 1 block/CU. LDS: WR/WF slices (16x520 f32 each) + 1KB bit table.
// Spike exchange: ballot-packed u32 masks through LLC (relaxed agent
// atomics) + per-group arrival counter (r6 protocol, 32 arrivals).
// ---------------------------------------------------------------------------
__global__ __launch_bounds__(256, 1) void k_rec(
    const float* __restrict__ XW,
    const float* __restrict__ Wrec, const float* __restrict__ Wff,
    const float* __restrict__ alpha_rec, const float* __restrict__ beta_rec,
    const float* __restrict__ b_rec,
    const float* __restrict__ b_ff, const float* __restrict__ alpha_ff,
    const float* __restrict__ beta_ff,
    u32* __restrict__ ring32, u32* __restrict__ spkb32, u32* __restrict__ cnt)
{
  __shared__ float WR[16 * 520];   // 33280 B
  __shared__ float WF[16 * 520];   // 33280 B
  __shared__ u32   Bits[16][16];   // [row][kb]: ch 32kb..32kb+31

  const int tid  = threadIdx.x;
  const int g    = blockIdx.x & 7;
  const int c    = blockIdx.x >> 3;       // member 0..31
  const int n0   = g * 16;
  const int lane = tid & 63;
  const int jl   = tid & 15;              // channel within member
  const int row  = tid >> 4;              // group row 0..15
  const int q    = lane >> 4;             // row within wave (row = w*4+q)
  const int jj   = c * 16 + jl;           // global channel

  // stage weight slices
  for (int it = tid; it < 2048; it += 256) {
    const int r16 = it >> 7, k4 = (it & 127) * 4;
    *(float4*)(WR + r16 * 520 + k4) = *(const float4*)(Wrec + (c * 16 + r16) * 512 + k4);
    *(float4*)(WF + r16 * 520 + k4) = *(const float4*)(Wff  + (c * 16 + r16) * 512 + k4);
  }

  const float ars = alpha_rec[jj], brs = beta_rec[jj];
  const float afs = alpha_ff[jj],  bfs = beta_ff[jj];
  const float brecs = b_rec[jj],   bffs = b_ff[jj];

  float synR = 0.f, memR = 0.f, spkR = 0.f;
  float synF = 0.f, memF = 0.f, spkF = 0.f;

  u32* cg = cnt + g * 32;
  const float* wrp = WR + jl * 520;
  const float* wfp = WF + jl * 520;

  __syncthreads();  // weights ready

  for (int tp = 0; tp <= TSTEPS; ++tp) {
    // prefetch XW for this step (independent of spikes)
    float xw = 0.f;
    if (tp < TSTEPS)
      xw = XW[((tp >> 1) * 128 + n0 + row) * 512 + jj];

    float SR = 0.f, SF = 0.f;

    if (tp > 0) {
      if (tid == 0) {
        const u32 tgt = 32u * (u32)tp;
        while (__hip_atomic_load(cg, __ATOMIC_ACQUIRE, __HIP_MEMORY_SCOPE_AGENT) < tgt)
          __builtin_amdgcn_s_sleep(1);
      }
      __syncthreads();

      { // stage spike bits: thread (row, jl) builds ch 32jl..32jl+31 of row
        const u32* src = ring32 + (((tp & 1) ^ 1) * 128 + n0 + row) * 32 + 2 * jl;
        u32 m0 = __hip_atomic_load(src,     __ATOMIC_RELAXED, __HIP_MEMORY_SCOPE_AGENT);
        u32 m1 = __hip_atomic_load(src + 1, __ATOMIC_RELAXED, __HIP_MEMORY_SCOPE_AGENT);
        Bits[row][jl] = (m0 & 0xFFFFu) | (m1 << 16);
      }
      __syncthreads();

      // BLAS-faithful GEMMs: seq-FMA ascending k, chunks split at k=384
      float aRA = 0.f, aRB = 0.f, aFA = 0.f, aFB = 0.f;
      for (int kb = 0; kb < 12; ++kb) {          // k = [0, 384)
        const u32 bw = Bits[row][kb];
#pragma unroll
        for (int k4 = 0; k4 < 32; k4 += 4) {
          const float4 wr4 = *(const float4*)(wrp + kb * 32 + k4);
          const float4 wf4 = *(const float4*)(wfp + kb * 32 + k4);
          const float b0 = (float)((bw >> (k4 + 0)) & 1u);
          const float b1 = (float)((bw >> (k4 + 1)) & 1u);
          const float b2 = (float)((bw >> (k4 + 2)) & 1u);
          const float b3 = (float)((bw >> (k4 + 3)) & 1u);
          aRA = __builtin_fmaf(b0, wr4.x, aRA); aFA = __builtin_fmaf(b0, wf4.x, aFA);
          aRA = __builtin_fmaf(b1, wr4.y, aRA); aFA = __builtin_fmaf(b1, wf4.y, aFA);
          aRA = __builtin_fmaf(b2, wr4.z, aRA); aFA = __builtin_fmaf(b2, wf4.z, aFA);
          aRA = __builtin_fmaf(b3, wr4.w, aRA); aFA = __builtin_fmaf(b3, wf4.w, aFA);
        }
      }
      for (int kb = 12; kb < 16; ++kb) {         // k = [384, 512)
        const u32 bw = Bits[row][kb];
#pragma unroll
        for (int k4 = 0; k4 < 32; k4 += 4) {
          const float4 wr4 = *(const float4*)(wrp + kb * 32 + k4);
          const float4 wf4 = *(const float4*)(wfp + kb * 32 + k4);
          const float b0 = (float)((bw >> (k4 + 0)) & 1u);
          const float b1 = (float)((bw >> (k4 + 1)) & 1u);
          const float b2 = (float)((bw >> (k4 + 2)) & 1u);
          const float b3 = (float)((bw >> (k4 + 3)) & 1u);
          aRB = __builtin_fmaf(b0, wr4.x, aRB); aFB = __builtin_fmaf(b0, wf4.x, aFB);
          aRB = __builtin_fmaf(b1, wr4.y, aRB); aFB = __builtin_fmaf(b1, wf4.y, aFB);
          aRB = __builtin_fmaf(b2, wr4.z, aRB); aFB = __builtin_fmaf(b2, wf4.z, aFB);
          aRB = __builtin_fmaf(b3, wr4.w, aRB); aFB = __builtin_fmaf(b3, wf4.w, aFB);
        }
      }
      SR = __fadd_rn(aRA, aRB);
      SF = __fadd_rn(aFA, aFB);

      // ff epilogue for step tp-1
      {
        float curf = __fadd_rn(SF, bffs);
        synF = __fadd_rn(__fmul_rn(afs, synF), curf);
        memF = __fsub_rn(__fadd_rn(__fmul_rn(bfs, memF), synF), spkF);
        spkF = (memF > 1.0f) ? 1.0f : 0.0f;
        const u64 B = __ballot(spkF != 0.f);
        if (jl == 0)
          __hip_atomic_store(spkb32 + ((u64)(tp - 1) * 128 + n0 + row) * 32 + c,
                             (u32)((B >> (16 * q)) & 0xFFFFull),
                             __ATOMIC_RELAXED, __HIP_MEMORY_SCOPE_AGENT);
      }
    }

    if (tp < TSTEPS) {
      // rec epilogue for step tp
      float cur = __fadd_rn(__fadd_rn(xw, SR), brecs);
      synR = __fadd_rn(__fmul_rn(ars, synR), cur);
      memR = __fsub_rn(__fadd_rn(__fmul_rn(brs, memR), synR), spkR);
      spkR = (memR > 1.0f) ? 1.0f : 0.0f;
      const u64 B = __ballot(spkR != 0.f);
      if (jl == 0)
        __hip_atomic_store(ring32 + ((tp & 1) * 128 + n0 + row) * 32 + c,
                           (u32)((B >> (16 * q)) & 0xFFFFull),
                           __ATOMIC_RELAXED, __HIP_MEMORY_SCOPE_AGENT);
    }
    __syncthreads();   // drains vmcnt: all stores complete before arrival

    if (tp < TSTEPS && tid == 0)
      __hip_atomic_fetch_add(cg, 1u, __ATOMIC_RELEASE, __HIP_MEMORY_SCOPE_AGENT);
  }
}

// ---------------------------------------------------------------------------
// k_c3: c3[row,j] = R(R(seqA+seqB) + bias) from spike bitmasks.
// grid 2048 (32 rows each), block 256: thread = (j 0..127, rh 0..1 -> 16 rows).
// k-outer with coalesced WT loads; bits from LDS words (member m = k>>4).
// ---------------------------------------------------------------------------
__global__ __launch_bounds__(256) void k_c3(
    const u32* __restrict__ spkb32, const float* __restrict__ WT,
    const float* __restrict__ bmu, const float* __restrict__ blv,
    float* __restrict__ c3)
{
  __shared__ u32 Bc[32][32];    // [row][member]
  const int tid  = threadIdx.x;
  const int rows0 = blockIdx.x * 32;

  for (int it = tid; it < 1024; it += 256)
    ((u32*)Bc)[it] = spkb32[(u64)rows0 * 32 + it];
  __syncthreads();

  const int j  = tid & 127;
  const int rh = tid >> 7;        // 16 rows each
  const float bias = (j < 64) ? bmu[j] : blv[j - 64];

  float accA[16], accB[16];
#pragma unroll
  for (int r = 0; r < 16; ++r) { accA[r] = 0.f; accB[r] = 0.f; }

  for (int m = 0; m < 24; ++m) {              // k = [0, 384)
    u32 wrow[16];
#pragma unroll
    for (int r = 0; r < 16; ++r) wrow[r] = Bc[rh * 16 + r][m];
    const float* wp = WT + (m * 16) * 128 + j;
#pragma unroll
    for (int kk = 0; kk < 16; ++kk) {
      const float wv = wp[kk * 128];          // coalesced
#pragma unroll
      for (int r = 0; r < 16; ++r) {
        const float b = (float)((wrow[r] >> kk) & 1u);
        accA[r] = __builtin_fmaf(b, wv, accA[r]);
      }
    }
  }
  for (int m = 24; m < 32; ++m) {             // k = [384, 512)
    u32 wrow[16];
#pragma unroll
    for (int r = 0; r < 16; ++r) wrow[r] = Bc[rh * 16 + r][m];
    const float* wp = WT + (m * 16) * 128 + j;
#pragma unroll
    for (int kk = 0; kk < 16; ++kk) {
      const float wv = wp[kk * 128];
#pragma unroll
      for (int r = 0; r < 16; ++r) {
        const float b = (float)((wrow[r] >> kk) & 1u);
        accB[r] = __builtin_fmaf(b, wv, accB[r]);
      }
    }
  }

#pragma unroll
  for (int r = 0; r < 16; ++r)
    c3[(u64)(rows0 + rh * 16 + r) * 128 + j] =
        __fadd_rn(__fadd_rn(accA[r], accB[r]), bias);
}

// ---------------------------------------------------------------------------
// k_scan: mem[t'] = R(R(beta*mem) + c3[t']), store every t'.  (r6 verbatim)
// ---------------------------------------------------------------------------
__global__ __launch_bounds__(256) void k_scan(
    const float* __restrict__ c3,
    const float* __restrict__ beta_mu, const float* __restrict__ beta_lv,
    float* __restrict__ Mem)
{
  const int tid = blockIdx.x * 256 + threadIdx.x;
  const int n = tid >> 7, ap = tid & 127;
  const float beta = (ap < 64) ? beta_mu[ap] : beta_lv[ap - 64];
  const float* src = c3 + n * 128 + ap;
  float* dst = Mem + n * 128 + ap;
  float mem = 0.0f;
  for (int t = 0; t < 512; ++t) {
    mem = __fadd_rn(__fmul_rn(beta, mem), src[(u64)t * 16384]);
    dst[(u64)t * 16384] = mem;
  }
}

// ---------------------------------------------------------------------------
// k_out: out = R(mu0+mu1)*0.5, mu = seqFMA_64.  (r6 verbatim)
// ---------------------------------------------------------------------------
__global__ __launch_bounds__(256) void k_out(
    const float* __restrict__ Mem,
    const float* __restrict__ Wmu_out, const float* __restrict__ Wlv_out,
    float* __restrict__ out)
{
  const int tid = blockIdx.x * 256 + threadIdx.x;
  const int a = tid & 7;
  const int n = (tid >> 3) & 127;
  const int t = (tid >> 10) & 255;
  const int kind = tid >> 18;
  const float* wv = ((kind == 0) ? Wmu_out : Wlv_out) + a * 64;
  const float* s0 = Mem + ((u64)(2 * t) * 128 + n) * 128 + kind * 64;
  const float* s1 = Mem + ((u64)(2 * t + 1) * 128 + n) * 128 + kind * 64;
  float mu0 = 0.0f, mu1 = 0.0f;
#pragma unroll 8
  for (int q = 0; q < 64; ++q) mu0 = __builtin_fmaf(s0[q], wv[q], mu0);
#pragma unroll 8
  for (int q = 0; q < 64; ++q) mu1 = __builtin_fmaf(s1[q], wv[q], mu1);
  out[tid] = __fmul_rn(__fadd_rn(mu0, mu1), 0.5f);
}

// ---------------------------------------------------------------------------
extern "C" void kernel_launch(void* const* d_in, const int* in_sizes, int n_in,
                              void* d_out, int out_size, void* d_ws, size_t ws_size,
                              hipStream_t stream) {
  (void)in_sizes; (void)n_in; (void)out_size;
  if (ws_size < WS_NEED) return;

  const float* state     = (const float*)d_in[0];
  const float* target    = (const float*)d_in[1];
  const float* W_rec_in  = (const float*)d_in[2];
  const float* b_rec_in  = (const float*)d_in[3];
  const float* W_rec     = (const float*)d_in[4];
  const float* b_rec     = (const float*)d_in[5];
  const float* alpha_rec = (const float*)d_in[6];
  const float* beta_rec  = (const float*)d_in[7];
  const float* W_ff_in   = (const float*)d_in[8];
  const float* b_ff_in   = (const float*)d_in[9];
  const float* alpha_ff  = (const float*)d_in[10];
  const float* beta_ff   = (const float*)d_in[11];
  const float* W_mu_in   = (const float*)d_in[12];
  const float* b_mu_in   = (const float*)d_in[13];
  const float* beta_mu   = (const float*)d_in[14];
  const float* W_mu_out  = (const float*)d_in[15];
  const float* W_lv_in   = (const float*)d_in[16];
  const float* b_lv_in   = (const float*)d_in[17];
  const float* beta_lv   = (const float*)d_in[18];
  const float* W_lv_out  = (const float*)d_in[19];

  char* ws = (char*)d_ws;
  float* XW    = (float*)(ws + XW_OFF);
  float* c3    = (float*)(ws + C3_OFF);
  float* Mem   = (float*)(ws + MEM_OFF);
  u32*   spkb32= (u32*)  (ws + SPKB_OFF);
  float* WT    = (float*)(ws + WT_OFF);
  float* WinT  = (float*)(ws + WINT_OFF);
  u32*   ring32= (u32*)  (ws + RING_OFF);
  u32*   cnt   = (u32*)  (ws + CNT_OFF);

  hipMemsetAsync(cnt, 0, 4096, stream);

  hipLaunchKernelGGL(k_prepT, dim3(512), dim3(256), 0, stream,
                     W_rec_in, W_mu_in, W_lv_in, WinT, WT);
  hipLaunchKernelGGL(k_xw, dim3(2048), dim3(256), 0, stream,
                     state, target, WinT, b_rec_in, XW);
  hipLaunchKernelGGL(k_rec, dim3(256), dim3(256), 0, stream,
                     XW, W_rec, W_ff_in,
                     alpha_rec, beta_rec, b_rec,
                     b_ff_in, alpha_ff, beta_ff, ring32, spkb32, cnt);
  hipLaunchKernelGGL(k_c3, dim3(2048), dim3(256), 0, stream,
                     spkb32, WT, b_mu_in, b_lv_in, c3);
  hipLaunchKernelGGL(k_scan, dim3(64), dim3(256), 0, stream,
                     c3, beta_mu, beta_lv, Mem);
  hipLaunchKernelGGL(k_out, dim3(2048), dim3(256), 0, stream,
                     Mem, W_mu_out, W_lv_out, (float*)d_out);
}

// Round 8
// 7844.750 us; speedup vs baseline: 2.0407x; 1.0711x over previous
//
#include <hip/hip_runtime.h>

// ---------------------------------------------------------------------------
// PolicyNetRSNNPB forward, MI355X/gfx950.  Round 8: k_rec LDS restructure.
// r7 passed (8.4 ms). Arithmetic is FROZEN (numpy-fp32 emulation):
//   * GEMM accumulator: sequential-k FMA ascending, K=512 split [0,384)+
//     [384,512) merged by one fadd; * elementwise single-rounded, no FMA
//     contraction. Any change below preserves per-accumulator order exactly.
// Changes vs r7:
//  k_rec : (1) weight pad 520 -> 516 (2-way LDS conflict = free; r7's 520
//          caused 4-way on ds_read_b128 -> 1.29e9 conflict cycles).
//          (2) WAVE SPECIALIZATION: waves 0-1 compute rec GEMM only, waves
//          2-3 ff GEMM only; lane = (ch 0..15, rowpair 0..3) handles 2 rows
//          of one matrix -> per-CU LDS instruction cadence halves.
//  k_prepT/k_xw/k_c3/k_scan/k_out: unchanged from r7.
// ---------------------------------------------------------------------------

typedef unsigned int       u32;
typedef unsigned short     u16;
typedef unsigned long long u64;
typedef unsigned char      u8;

#define TSTEPS 512
#define HIDDEN 512

// workspace layout (bytes) — unchanged from r7.
#define XW_OFF    0ull
#define C3_OFF    0ull
#define MEM_OFF   33554432ull
#define SPKB_OFF  100663296ull
#define WT_OFF    109051904ull
#define WINT_OFF  109314048ull
#define RING_OFF  134217728ull
#define CNT_OFF   134742016ull
#define WS_NEED   (134742016ull + 4096ull)

#define QCHUNK 384

// ---------------------------------------------------------------------------
__global__ __launch_bounds__(256) void k_prepT(
    const float* __restrict__ Win,
    const float* __restrict__ Wmu, const float* __restrict__ Wlv,
    float* __restrict__ WinT, float* __restrict__ WT)
{
  const int idx = blockIdx.x * 256 + threadIdx.x;
  if (idx < 65536) {
    const int k = idx >> 9, j = idx & 511;
    WinT[idx] = Win[j * 128 + k];
  } else {
    const int i2 = idx - 65536;
    const int k = i2 >> 7, j = i2 & 127;
    WT[i2] = (j < 64) ? Wmu[j * 512 + k] : Wlv[(j - 64) * 512 + k];
  }
}

// ---------------------------------------------------------------------------
__global__ __launch_bounds__(256) void k_xw(
    const float* __restrict__ state, const float* __restrict__ target,
    const float* __restrict__ WinT, const float* __restrict__ b_in,
    float* __restrict__ XW)
{
  __shared__ float xs[16][129];
  const int tid  = threadIdx.x;
  const int row0 = blockIdx.x * 16;

  for (int e = tid; e < 2048; e += 256) {
    int r = e >> 7, k = e & 127;
    xs[r][k] = (k < 64) ? state[(row0 + r) * 64 + k]
                        : target[(row0 + r) * 64 + k - 64];
  }
  __syncthreads();

#pragma unroll
  for (int jh = 0; jh < 2; ++jh) {
    const int j = jh * 256 + tid;
    float acc[16];
#pragma unroll
    for (int r = 0; r < 16; ++r) acc[r] = 0.0f;
    for (int k = 0; k < 128; ++k) {
      const float wv = WinT[k * 512 + j];
#pragma unroll
      for (int r = 0; r < 16; ++r)
        acc[r] = __builtin_fmaf(xs[r][k], wv, acc[r]);
    }
    const float b = b_in[j];
#pragma unroll
    for (int r = 0; r < 16; ++r)
      XW[(row0 + r) * 512 + j] = __fadd_rn(acc[r], b);
  }
}

// ---------------------------------------------------------------------------
// k_rec: grid 256 = 8 groups x 32 members, block 256 = 4 waves.
// Waves 0-1: rec GEMM (+rec epilogue/ring).  Waves 2-3: ff GEMM (+spkf).
// Lane = (ch 0..15, rp 0..3) -> rows {8*(wv&1)+2rp, +1} of its matrix.
// LDS: WR/WF 16x516 f32 (2-way-free) + Bits[16][17].
// ---------------------------------------------------------------------------
__global__ __launch_bounds__(256, 1) void k_rec(
    const float* __restrict__ XW,
    const float* __restrict__ Wrec, const float* __restrict__ Wff,
    const float* __restrict__ alpha_rec, const float* __restrict__ beta_rec,
    const float* __restrict__ b_rec,
    const float* __restrict__ b_ff, const float* __restrict__ alpha_ff,
    const float* __restrict__ beta_ff,
    u32* __restrict__ ring32, u32* __restrict__ spkb32, u32* __restrict__ cnt)
{
  __shared__ float WR[16 * 516];   // 33024 B
  __shared__ float WF[16 * 516];   // 33024 B
  __shared__ u32   Bits[16][17];   // [row][kb], pad 17 (rows 2 apart != same bank)

  const int tid  = threadIdx.x;
  const int g    = blockIdx.x & 7;
  const int c    = blockIdx.x >> 3;
  const int n0   = g * 16;
  const int wv   = tid >> 6;              // wave 0..3
  const int lane = tid & 63;
  const int ch   = lane & 15;             // channel within member
  const int rp   = lane >> 4;             // row-pair 0..3
  const int rowb = 8 * (wv & 1) + 2 * rp; // first of this lane's two rows
  const bool isFF = (wv >= 2);
  const int jj   = c * 16 + ch;

  // stage weight slices (516-padded: bank offset 4*row16 -> 2-way = free)
  for (int it = tid; it < 2048; it += 256) {
    const int r16 = it >> 7, k4 = (it & 127) * 4;
    *(float4*)(WR + r16 * 516 + k4) = *(const float4*)(Wrec + (c * 16 + r16) * 512 + k4);
    *(float4*)(WF + r16 * 516 + k4) = *(const float4*)(Wff  + (c * 16 + r16) * 512 + k4);
  }

  // per-wave coefficients (only the ones this wave needs)
  float coA = 0.f, coB = 0.f, coC = 0.f;
  if (!isFF) { coA = alpha_rec[jj]; coB = beta_rec[jj]; coC = b_rec[jj]; }
  else       { coA = alpha_ff[jj];  coB = beta_ff[jj];  coC = b_ff[jj]; }

  float syn[2] = {0.f, 0.f}, mem[2] = {0.f, 0.f}, spk[2] = {0.f, 0.f};

  const float* wp = (isFF ? WF : WR) + ch * 516;
  const int srow = tid >> 4;   // staging row 0..15
  const int sjl  = tid & 15;   // staging word 0..15
  u32* cg = cnt + g * 32;

  __syncthreads();  // weights ready

  for (int tp = 0; tp <= TSTEPS; ++tp) {
    // rec waves prefetch XW for step tp
    float xw[2] = {0.f, 0.f};
    if (!isFF && tp < TSTEPS) {
      const float* ph = XW + ((tp >> 1) * 128 + n0 + rowb) * 512 + jj;
      xw[0] = ph[0];
      xw[1] = ph[512];
    }

    float SA[2] = {0.f, 0.f};   // merged GEMM results for the 2 rows

    if (tp > 0) {
      if (tid == 0) {
        const u32 tgt = 32u * (u32)tp;
        while (__hip_atomic_load(cg, __ATOMIC_ACQUIRE, __HIP_MEMORY_SCOPE_AGENT) < tgt)
          __builtin_amdgcn_s_sleep(1);
      }
      __syncthreads();

      { // stage spike bits of step tp-1 (1 word per thread)
        const u32* src = ring32 + (((tp & 1) ^ 1) * 128 + n0 + srow) * 32 + 2 * sjl;
        u32 m0 = __hip_atomic_load(src,     __ATOMIC_RELAXED, __HIP_MEMORY_SCOPE_AGENT);
        u32 m1 = __hip_atomic_load(src + 1, __ATOMIC_RELAXED, __HIP_MEMORY_SCOPE_AGENT);
        Bits[srow][sjl] = (m0 & 0xFFFFu) | (m1 << 16);
      }
      __syncthreads();

      // BLAS-faithful GEMM (one matrix, two rows): seq-FMA ascending k,
      // chunk split at kb=12 (k=384). Order per accumulator == r6/r7.
      float a0A = 0.f, a0B = 0.f, a1A = 0.f, a1B = 0.f;
      for (int kb = 0; kb < 12; ++kb) {
        const u32 w0 = Bits[rowb][kb];
        const u32 w1 = Bits[rowb + 1][kb];
#pragma unroll
        for (int k4 = 0; k4 < 32; k4 += 4) {
          const float4 w4 = *(const float4*)(wp + kb * 32 + k4);
#pragma unroll
          for (int i = 0; i < 4; ++i) {
            const float wvv = (i == 0) ? w4.x : (i == 1) ? w4.y : (i == 2) ? w4.z : w4.w;
            a0A = __builtin_fmaf((float)((w0 >> (k4 + i)) & 1u), wvv, a0A);
            a1A = __builtin_fmaf((float)((w1 >> (k4 + i)) & 1u), wvv, a1A);
          }
        }
      }
      for (int kb = 12; kb < 16; ++kb) {
        const u32 w0 = Bits[rowb][kb];
        const u32 w1 = Bits[rowb + 1][kb];
#pragma unroll
        for (int k4 = 0; k4 < 32; k4 += 4) {
          const float4 w4 = *(const float4*)(wp + kb * 32 + k4);
#pragma unroll
          for (int i = 0; i < 4; ++i) {
            const float wvv = (i == 0) ? w4.x : (i == 1) ? w4.y : (i == 2) ? w4.z : w4.w;
            a0B = __builtin_fmaf((float)((w0 >> (k4 + i)) & 1u), wvv, a0B);
            a1B = __builtin_fmaf((float)((w1 >> (k4 + i)) & 1u), wvv, a1B);
          }
        }
      }
      SA[0] = __fadd_rn(a0A, a0B);
      SA[1] = __fadd_rn(a1A, a1B);
    }

    if (isFF) {
      // ff epilogue for step tp-1
      if (tp > 0) {
#pragma unroll
        for (int i = 0; i < 2; ++i) {
          float curf = __fadd_rn(SA[i], coC);
          syn[i] = __fadd_rn(__fmul_rn(coA, syn[i]), curf);
          mem[i] = __fsub_rn(__fadd_rn(__fmul_rn(coB, mem[i]), syn[i]), spk[i]);
          spk[i] = (mem[i] > 1.0f) ? 1.0f : 0.0f;
        }
        const u64 B0 = __ballot(spk[0] != 0.f);
        const u64 B1 = __ballot(spk[1] != 0.f);
        if (ch == 0) {
          const u64 base = ((u64)(tp - 1) * 128 + n0 + rowb) * 32 + c;
          __hip_atomic_store(spkb32 + base,      (u32)((B0 >> (16 * rp)) & 0xFFFFull),
                             __ATOMIC_RELAXED, __HIP_MEMORY_SCOPE_AGENT);
          __hip_atomic_store(spkb32 + base + 32, (u32)((B1 >> (16 * rp)) & 0xFFFFull),
                             __ATOMIC_RELAXED, __HIP_MEMORY_SCOPE_AGENT);
        }
      }
    } else {
      // rec epilogue for step tp
      if (tp < TSTEPS) {
#pragma unroll
        for (int i = 0; i < 2; ++i) {
          float cur = __fadd_rn(__fadd_rn(xw[i], SA[i]), coC);
          syn[i] = __fadd_rn(__fmul_rn(coA, syn[i]), cur);
          mem[i] = __fsub_rn(__fadd_rn(__fmul_rn(coB, mem[i]), syn[i]), spk[i]);
          spk[i] = (mem[i] > 1.0f) ? 1.0f : 0.0f;
        }
        const u64 B0 = __ballot(spk[0] != 0.f);
        const u64 B1 = __ballot(spk[1] != 0.f);
        if (ch == 0) {
          const int base = ((tp & 1) * 128 + n0 + rowb) * 32 + c;
          __hip_atomic_store(ring32 + base,      (u32)((B0 >> (16 * rp)) & 0xFFFFull),
                             __ATOMIC_RELAXED, __HIP_MEMORY_SCOPE_AGENT);
          __hip_atomic_store(ring32 + base + 32, (u32)((B1 >> (16 * rp)) & 0xFFFFull),
                             __ATOMIC_RELAXED, __HIP_MEMORY_SCOPE_AGENT);
        }
      }
    }
    __syncthreads();   // drains vmcnt: ring stores complete before arrival

    if (tp < TSTEPS && tid == 0)
      __hip_atomic_fetch_add(cg, 1u, __ATOMIC_RELEASE, __HIP_MEMORY_SCOPE_AGENT);
  }
}

// ---------------------------------------------------------------------------
__global__ __launch_bounds__(256) void k_c3(
    const u32* __restrict__ spkb32, const float* __restrict__ WT,
    const float* __restrict__ bmu, const float* __restrict__ blv,
    float* __restrict__ c3)
{
  __shared__ u32 Bc[32][32];
  const int tid  = threadIdx.x;
  const int rows0 = blockIdx.x * 32;

  for (int it = tid; it < 1024; it += 256)
    ((u32*)Bc)[it] = spkb32[(u64)rows0 * 32 + it];
  __syncthreads();

  const int j  = tid & 127;
  const int rh = tid >> 7;
  const float bias = (j < 64) ? bmu[j] : blv[j - 64];

  float accA[16], accB[16];
#pragma unroll
  for (int r = 0; r < 16; ++r) { accA[r] = 0.f; accB[r] = 0.f; }

  for (int m = 0; m < 24; ++m) {
    u32 wrow[16];
#pragma unroll
    for (int r = 0; r < 16; ++r) wrow[r] = Bc[rh * 16 + r][m];
    const float* wpp = WT + (m * 16) * 128 + j;
#pragma unroll
    for (int kk = 0; kk < 16; ++kk) {
      const float wvv = wpp[kk * 128];
#pragma unroll
      for (int r = 0; r < 16; ++r) {
        const float b = (float)((wrow[r] >> kk) & 1u);
        accA[r] = __builtin_fmaf(b, wvv, accA[r]);
      }
    }
  }
  for (int m = 24; m < 32; ++m) {
    u32 wrow[16];
#pragma unroll
    for (int r = 0; r < 16; ++r) wrow[r] = Bc[rh * 16 + r][m];
    const float* wpp = WT + (m * 16) * 128 + j;
#pragma unroll
    for (int kk = 0; kk < 16; ++kk) {
      const float wvv = wpp[kk * 128];
#pragma unroll
      for (int r = 0; r < 16; ++r) {
        const float b = (float)((wrow[r] >> kk) & 1u);
        accB[r] = __builtin_fmaf(b, wvv, accB[r]);
      }
    }
  }

#pragma unroll
  for (int r = 0; r < 16; ++r)
    c3[(u64)(rows0 + rh * 16 + r) * 128 + j] =
        __fadd_rn(__fadd_rn(accA[r], accB[r]), bias);
}

// ---------------------------------------------------------------------------
__global__ __launch_bounds__(256) void k_scan(
    const float* __restrict__ c3,
    const float* __restrict__ beta_mu, const float* __restrict__ beta_lv,
    float* __restrict__ Mem)
{
  const int tid = blockIdx.x * 256 + threadIdx.x;
  const int n = tid >> 7, ap = tid & 127;
  const float beta = (ap < 64) ? beta_mu[ap] : beta_lv[ap - 64];
  const float* src = c3 + n * 128 + ap;
  float* dst = Mem + n * 128 + ap;
  float mem = 0.0f;
  for (int t = 0; t < 512; ++t) {
    mem = __fadd_rn(__fmul_rn(beta, mem), src[(u64)t * 16384]);
    dst[(u64)t * 16384] = mem;
  }
}

// ---------------------------------------------------------------------------
__global__ __launch_bounds__(256) void k_out(
    const float* __restrict__ Mem,
    const float* __restrict__ Wmu_out, const float* __restrict__ Wlv_out,
    float* __restrict__ out)
{
  const int tid = blockIdx.x * 256 + threadIdx.x;
  const int a = tid & 7;
  const int n = (tid >> 3) & 127;
  const int t = (tid >> 10) & 255;
  const int kind = tid >> 18;
  const float* wv = ((kind == 0) ? Wmu_out : Wlv_out) + a * 64;
  const float* s0 = Mem + ((u64)(2 * t) * 128 + n) * 128 + kind * 64;
  const float* s1 = Mem + ((u64)(2 * t + 1) * 128 + n) * 128 + kind * 64;
  float mu0 = 0.0f, mu1 = 0.0f;
#pragma unroll 8
  for (int q = 0; q < 64; ++q) mu0 = __builtin_fmaf(s0[q], wv[q], mu0);
#pragma unroll 8
  for (int q = 0; q < 64; ++q) mu1 = __builtin_fmaf(s1[q], wv[q], mu1);
  out[tid] = __fmul_rn(__fadd_rn(mu0, mu1), 0.5f);
}

// ---------------------------------------------------------------------------
extern "C" void kernel_launch(void* const* d_in, const int* in_sizes, int n_in,
                              void* d_out, int out_size, void* d_ws, size_t ws_size,
                              hipStream_t stream) {
  (void)in_sizes; (void)n_in; (void)out_size;
  if (ws_size < WS_NEED) return;

  const float* state     = (const float*)d_in[0];
  const float* target    = (const float*)d_in[1];
  const float* W_rec_in  = (const float*)d_in[2];
  const float* b_rec_in  = (const float*)d_in[3];
  const float* W_rec     = (const float*)d_in[4];
  const float* b_rec     = (const float*)d_in[5];
  const float* alpha_rec = (const float*)d_in[6];
  const float* beta_rec  = (const float*)d_in[7];
  const float* W_ff_in   = (const float*)d_in[8];
  const float* b_ff_in   = (const float*)d_in[9];
  const float* alpha_ff  = (const float*)d_in[10];
  const float* beta_ff   = (const float*)d_in[11];
  const float* W_mu_in   = (const float*)d_in[12];
  const float* b_mu_in   = (const float*)d_in[13];
  const float* beta_mu   = (const float*)d_in[14];
  const float* W_mu_out  = (const float*)d_in[15];
  const float* W_lv_in   = (const float*)d_in[16];
  const float* b_lv_in   = (const float*)d_in[17];
  const float* beta_lv   = (const float*)d_in[18];
  const float* W_lv_out  = (const float*)d_in[19];

  char* ws = (char*)d_ws;
  float* XW    = (float*)(ws + XW_OFF);
  float* c3    = (float*)(ws + C3_OFF);
  float* Mem   = (float*)(ws + MEM_OFF);
  u32*   spkb32= (u32*)  (ws + SPKB_OFF);
  float* WT    = (float*)(ws + WT_OFF);
  float* WinT  = (float*)(ws + WINT_OFF);
  u32*   ring32= (u32*)  (ws + RING_OFF);
  u32*   cnt   = (u32*)  (ws + CNT_OFF);

  hipMemsetAsync(cnt, 0, 4096, stream);

  hipLaunchKernelGGL(k_prepT, dim3(512), dim3(256), 0, stream,
                     W_rec_in, W_mu_in, W_lv_in, WinT, WT);
  hipLaunchKernelGGL(k_xw, dim3(2048), dim3(256), 0, stream,
                     state, target, WinT, b_rec_in, XW);
  hipLaunchKernelGGL(k_rec, dim3(256), dim3(256), 0, stream,
                     XW, W_rec, W_ff_in,
                     alpha_rec, beta_rec, b_rec,
                     b_ff_in, alpha_ff, beta_ff, ring32, spkb32, cnt);
  hipLaunchKernelGGL(k_c3, dim3(2048), dim3(256), 0, stream,
                     spkb32, WT, b_mu_in, b_lv_in, c3);
  hipLaunchKernelGGL(k_scan, dim3(64), dim3(256), 0, stream,
                     c3, beta_mu, beta_lv, Mem);
  hipLaunchKernelGGL(k_out, dim3(2048), dim3(256), 0, stream,
                     Mem, W_mu_out, W_lv_out, (float*)d_out);
}

// Round 9
// 4885.818 us; speedup vs baseline: 3.2766x; 1.6056x over previous
//
#include <hip/hip_runtime.h>

// ---------------------------------------------------------------------------
// PolicyNetRSNNPB forward, MI355X/gfx950.  Round 9: kill the barrier latency.
// r8 passed (7.84 ms; k_rec 7.4 ms = 14.4 us/step, compute only ~2.6 us).
// Arithmetic FROZEN (numpy-fp32 emulation): seq-k FMA ascending per
// accumulator, K=512 split [0,384)+[384,512) merged by one fadd; elementwise
// single-rounded, no contraction. This round changes ONLY the k_rec sync:
//   (1) counter barrier -> DATA-EMBEDDED TAGS: ring word = (tp<<16)|mask16;
//       consumers poll the word until tag==tp-1 (one LLC flight instead of
//       store+fence+counter+poll chain). Slot reuse is safe: reaching step
//       tp+2 requires having seen all tags tp+1, which requires every member
//       to have consumed step tp.
//   (2) Bits double-buffered by step parity -> ONE __syncthreads per step.
//   (3) rec waves skip the dead GEMM at tp=TSTEPS.
// k_prepT/k_xw/k_c3/k_scan/k_out unchanged from r8.
// ---------------------------------------------------------------------------

typedef unsigned int       u32;
typedef unsigned short     u16;
typedef unsigned long long u64;
typedef unsigned char      u8;

#define TSTEPS 512
#define HIDDEN 512

// workspace layout (bytes) — unchanged from r7/r8.
#define XW_OFF    0ull
#define C3_OFF    0ull
#define MEM_OFF   33554432ull
#define SPKB_OFF  100663296ull
#define WT_OFF    109051904ull
#define WINT_OFF  109314048ull
#define RING_OFF  134217728ull
#define CNT_OFF   134742016ull
#define WS_NEED   (134742016ull + 4096ull)

#define QCHUNK 384

// ---------------------------------------------------------------------------
__global__ __launch_bounds__(256) void k_prepT(
    const float* __restrict__ Win,
    const float* __restrict__ Wmu, const float* __restrict__ Wlv,
    float* __restrict__ WinT, float* __restrict__ WT)
{
  const int idx = blockIdx.x * 256 + threadIdx.x;
  if (idx < 65536) {
    const int k = idx >> 9, j = idx & 511;
    WinT[idx] = Win[j * 128 + k];
  } else {
    const int i2 = idx - 65536;
    const int k = i2 >> 7, j = i2 & 127;
    WT[i2] = (j < 64) ? Wmu[j * 512 + k] : Wlv[(j - 64) * 512 + k];
  }
}

// ---------------------------------------------------------------------------
__global__ __launch_bounds__(256) void k_xw(
    const float* __restrict__ state, const float* __restrict__ target,
    const float* __restrict__ WinT, const float* __restrict__ b_in,
    float* __restrict__ XW)
{
  __shared__ float xs[16][129];
  const int tid  = threadIdx.x;
  const int row0 = blockIdx.x * 16;

  for (int e = tid; e < 2048; e += 256) {
    int r = e >> 7, k = e & 127;
    xs[r][k] = (k < 64) ? state[(row0 + r) * 64 + k]
                        : target[(row0 + r) * 64 + k - 64];
  }
  __syncthreads();

#pragma unroll
  for (int jh = 0; jh < 2; ++jh) {
    const int j = jh * 256 + tid;
    float acc[16];
#pragma unroll
    for (int r = 0; r < 16; ++r) acc[r] = 0.0f;
    for (int k = 0; k < 128; ++k) {
      const float wv = WinT[k * 512 + j];
#pragma unroll
      for (int r = 0; r < 16; ++r)
        acc[r] = __builtin_fmaf(xs[r][k], wv, acc[r]);
    }
    const float b = b_in[j];
#pragma unroll
    for (int r = 0; r < 16; ++r)
      XW[(row0 + r) * 512 + j] = __fadd_rn(acc[r], b);
  }
}

// ---------------------------------------------------------------------------
// k_rec: grid 256 = 8 groups x 32 members, block 256 = 4 waves.
// Waves 0-1: rec GEMM+epilogue (tagged ring stores). Waves 2-3: ff GEMM+
// epilogue (spkb32 history). Lane = (ch, rp) -> 2 rows of one matrix.
// Sync: per-word tag polling + one __syncthreads per step (Bits dbuf).
// ---------------------------------------------------------------------------
__global__ __launch_bounds__(256, 1) void k_rec(
    const float* __restrict__ XW,
    const float* __restrict__ Wrec, const float* __restrict__ Wff,
    const float* __restrict__ alpha_rec, const float* __restrict__ beta_rec,
    const float* __restrict__ b_rec,
    const float* __restrict__ b_ff, const float* __restrict__ alpha_ff,
    const float* __restrict__ beta_ff,
    u32* __restrict__ ring32, u32* __restrict__ spkb32)
{
  __shared__ float WR[16 * 516];     // 33024 B
  __shared__ float WF[16 * 516];     // 33024 B
  __shared__ u32   Bits[2][16][17];  // [step parity][row][kb]

  const int tid  = threadIdx.x;
  const int g    = blockIdx.x & 7;
  const int c    = blockIdx.x >> 3;
  const int n0   = g * 16;
  const int wv   = tid >> 6;
  const int lane = tid & 63;
  const int ch   = lane & 15;
  const int rp   = lane >> 4;
  const int rowb = 8 * (wv & 1) + 2 * rp;
  const bool isFF = (wv >= 2);
  const int jj   = c * 16 + ch;

  for (int it = tid; it < 2048; it += 256) {
    const int r16 = it >> 7, k4 = (it & 127) * 4;
    *(float4*)(WR + r16 * 516 + k4) = *(const float4*)(Wrec + (c * 16 + r16) * 512 + k4);
    *(float4*)(WF + r16 * 516 + k4) = *(const float4*)(Wff  + (c * 16 + r16) * 512 + k4);
  }

  float coA, coB, coC;
  if (!isFF) { coA = alpha_rec[jj]; coB = beta_rec[jj]; coC = b_rec[jj]; }
  else       { coA = alpha_ff[jj];  coB = beta_ff[jj];  coC = b_ff[jj]; }

  float syn[2] = {0.f, 0.f}, mem[2] = {0.f, 0.f}, spk[2] = {0.f, 0.f};

  const float* wp = (isFF ? WF : WR) + ch * 516;
  const int srow = tid >> 4;
  const int sjl  = tid & 15;

  __syncthreads();  // weights ready

  for (int tp = 0; tp <= TSTEPS; ++tp) {
    float xw[2] = {0.f, 0.f};
    if (!isFF && tp < TSTEPS) {
      const float* ph = XW + ((tp >> 1) * 128 + n0 + rowb) * 512 + jj;
      xw[0] = ph[0];
      xw[1] = ph[512];
    }

    float SA[2] = {0.f, 0.f};

    if (tp > 0) {
      const int bp = (tp - 1) & 1;
      { // stage spike bits of step tp-1 (tag-polled, 2 words per thread)
        const u32 exp = (u32)(tp - 1);
        const u32* src = ring32 + (bp * 128 + n0 + srow) * 32 + 2 * sjl;
        u32 m0 = __hip_atomic_load(src,     __ATOMIC_RELAXED, __HIP_MEMORY_SCOPE_AGENT);
        while ((m0 >> 16) != exp) {
          __builtin_amdgcn_s_sleep(1);
          m0 = __hip_atomic_load(src,     __ATOMIC_RELAXED, __HIP_MEMORY_SCOPE_AGENT);
        }
        u32 m1 = __hip_atomic_load(src + 1, __ATOMIC_RELAXED, __HIP_MEMORY_SCOPE_AGENT);
        while ((m1 >> 16) != exp) {
          __builtin_amdgcn_s_sleep(1);
          m1 = __hip_atomic_load(src + 1, __ATOMIC_RELAXED, __HIP_MEMORY_SCOPE_AGENT);
        }
        Bits[bp][srow][sjl] = (m0 & 0xFFFFu) | (m1 << 16);
      }
      __syncthreads();   // Bits[bp] complete; also bounds skew for dbuf reuse

      if (isFF || tp < TSTEPS) {
        // BLAS-faithful GEMM: seq-FMA ascending k, chunk split at kb=12.
        float a0A = 0.f, a0B = 0.f, a1A = 0.f, a1B = 0.f;
        for (int kb = 0; kb < 12; ++kb) {
          const u32 w0 = Bits[bp][rowb][kb];
          const u32 w1 = Bits[bp][rowb + 1][kb];
#pragma unroll
          for (int k4 = 0; k4 < 32; k4 += 4) {
            const float4 w4 = *(const float4*)(wp + kb * 32 + k4);
#pragma unroll
            for (int i = 0; i < 4; ++i) {
              const float wvv = (i == 0) ? w4.x : (i == 1) ? w4.y : (i == 2) ? w4.z : w4.w;
              a0A = __builtin_fmaf((float)((w0 >> (k4 + i)) & 1u), wvv, a0A);
              a1A = __builtin_fmaf((float)((w1 >> (k4 + i)) & 1u), wvv, a1A);
            }
          }
        }
        for (int kb = 12; kb < 16; ++kb) {
          const u32 w0 = Bits[bp][rowb][kb];
          const u32 w1 = Bits[bp][rowb + 1][kb];
#pragma unroll
          for (int k4 = 0; k4 < 32; k4 += 4) {
            const float4 w4 = *(const float4*)(wp + kb * 32 + k4);
#pragma unroll
            for (int i = 0; i < 4; ++i) {
              const float wvv = (i == 0) ? w4.x : (i == 1) ? w4.y : (i == 2) ? w4.z : w4.w;
              a0B = __builtin_fmaf((float)((w0 >> (k4 + i)) & 1u), wvv, a0B);
              a1B = __builtin_fmaf((float)((w1 >> (k4 + i)) & 1u), wvv, a1B);
            }
          }
        }
        SA[0] = __fadd_rn(a0A, a0B);
        SA[1] = __fadd_rn(a1A, a1B);
      }
    }

    if (isFF) {
      if (tp > 0) {
        // ff epilogue for step tp-1
#pragma unroll
        for (int i = 0; i < 2; ++i) {
          float curf = __fadd_rn(SA[i], coC);
          syn[i] = __fadd_rn(__fmul_rn(coA, syn[i]), curf);
          mem[i] = __fsub_rn(__fadd_rn(__fmul_rn(coB, mem[i]), syn[i]), spk[i]);
          spk[i] = (mem[i] > 1.0f) ? 1.0f : 0.0f;
        }
        const u64 B0 = __ballot(spk[0] != 0.f);
        const u64 B1 = __ballot(spk[1] != 0.f);
        if (ch == 0) {
          const u64 base = ((u64)(tp - 1) * 128 + n0 + rowb) * 32 + c;
          __hip_atomic_store(spkb32 + base,      (u32)((B0 >> (16 * rp)) & 0xFFFFull),
                             __ATOMIC_RELAXED, __HIP_MEMORY_SCOPE_AGENT);
          __hip_atomic_store(spkb32 + base + 32, (u32)((B1 >> (16 * rp)) & 0xFFFFull),
                             __ATOMIC_RELAXED, __HIP_MEMORY_SCOPE_AGENT);
        }
      }
    } else {
      if (tp < TSTEPS) {
        // rec epilogue for step tp; tagged ring store (tag = tp)
#pragma unroll
        for (int i = 0; i < 2; ++i) {
          float cur = __fadd_rn(__fadd_rn(xw[i], SA[i]), coC);
          syn[i] = __fadd_rn(__fmul_rn(coA, syn[i]), cur);
          mem[i] = __fsub_rn(__fadd_rn(__fmul_rn(coB, mem[i]), syn[i]), spk[i]);
          spk[i] = (mem[i] > 1.0f) ? 1.0f : 0.0f;
        }
        const u64 B0 = __ballot(spk[0] != 0.f);
        const u64 B1 = __ballot(spk[1] != 0.f);
        if (ch == 0) {
          const u32 tag = ((u32)tp) << 16;
          const int base = ((tp & 1) * 128 + n0 + rowb) * 32 + c;
          __hip_atomic_store(ring32 + base,
                             tag | (u32)((B0 >> (16 * rp)) & 0xFFFFull),
                             __ATOMIC_RELAXED, __HIP_MEMORY_SCOPE_AGENT);
          __hip_atomic_store(ring32 + base + 32,
                             tag | (u32)((B1 >> (16 * rp)) & 0xFFFFull),
                             __ATOMIC_RELAXED, __HIP_MEMORY_SCOPE_AGENT);
        }
      }
    }
    // no end-of-step barrier: Bits is double-buffered; the pre-GEMM barrier
    // bounds inter-wave skew to one step.
  }
}

// ---------------------------------------------------------------------------
__global__ __launch_bounds__(256) void k_c3(
    const u32* __restrict__ spkb32, const float* __restrict__ WT,
    const float* __restrict__ bmu, const float* __restrict__ blv,
    float* __restrict__ c3)
{
  __shared__ u32 Bc[32][32];
  const int tid  = threadIdx.x;
  const int rows0 = blockIdx.x * 32;

  for (int it = tid; it < 1024; it += 256)
    ((u32*)Bc)[it] = spkb32[(u64)rows0 * 32 + it];
  __syncthreads();

  const int j  = tid & 127;
  const int rh = tid >> 7;
  const float bias = (j < 64) ? bmu[j] : blv[j - 64];

  float accA[16], accB[16];
#pragma unroll
  for (int r = 0; r < 16; ++r) { accA[r] = 0.f; accB[r] = 0.f; }

  for (int m = 0; m < 24; ++m) {
    u32 wrow[16];
#pragma unroll
    for (int r = 0; r < 16; ++r) wrow[r] = Bc[rh * 16 + r][m];
    const float* wpp = WT + (m * 16) * 128 + j;
#pragma unroll
    for (int kk = 0; kk < 16; ++kk) {
      const float wvv = wpp[kk * 128];
#pragma unroll
      for (int r = 0; r < 16; ++r) {
        const float b = (float)((wrow[r] >> kk) & 1u);
        accA[r] = __builtin_fmaf(b, wvv, accA[r]);
      }
    }
  }
  for (int m = 24; m < 32; ++m) {
    u32 wrow[16];
#pragma unroll
    for (int r = 0; r < 16; ++r) wrow[r] = Bc[rh * 16 + r][m];
    const float* wpp = WT + (m * 16) * 128 + j;
#pragma unroll
    for (int kk = 0; kk < 16; ++kk) {
      const float wvv = wpp[kk * 128];
#pragma unroll
      for (int r = 0; r < 16; ++r) {
        const float b = (float)((wrow[r] >> kk) & 1u);
        accB[r] = __builtin_fmaf(b, wvv, accB[r]);
      }
    }
  }

#pragma unroll
  for (int r = 0; r < 16; ++r)
    c3[(u64)(rows0 + rh * 16 + r) * 128 + j] =
        __fadd_rn(__fadd_rn(accA[r], accB[r]), bias);
}

// ---------------------------------------------------------------------------
__global__ __launch_bounds__(256) void k_scan(
    const float* __restrict__ c3,
    const float* __restrict__ beta_mu, const float* __restrict__ beta_lv,
    float* __restrict__ Mem)
{
  const int tid = blockIdx.x * 256 + threadIdx.x;
  const int n = tid >> 7, ap = tid & 127;
  const float beta = (ap < 64) ? beta_mu[ap] : beta_lv[ap - 64];
  const float* src = c3 + n * 128 + ap;
  float* dst = Mem + n * 128 + ap;
  float mem = 0.0f;
  for (int t = 0; t < 512; ++t) {
    mem = __fadd_rn(__fmul_rn(beta, mem), src[(u64)t * 16384]);
    dst[(u64)t * 16384] = mem;
  }
}

// ---------------------------------------------------------------------------
__global__ __launch_bounds__(256) void k_out(
    const float* __restrict__ Mem,
    const float* __restrict__ Wmu_out, const float* __restrict__ Wlv_out,
    float* __restrict__ out)
{
  const int tid = blockIdx.x * 256 + threadIdx.x;
  const int a = tid & 7;
  const int n = (tid >> 3) & 127;
  const int t = (tid >> 10) & 255;
  const int kind = tid >> 18;
  const float* wv = ((kind == 0) ? Wmu_out : Wlv_out) + a * 64;
  const float* s0 = Mem + ((u64)(2 * t) * 128 + n) * 128 + kind * 64;
  const float* s1 = Mem + ((u64)(2 * t + 1) * 128 + n) * 128 + kind * 64;
  float mu0 = 0.0f, mu1 = 0.0f;
#pragma unroll 8
  for (int q = 0; q < 64; ++q) mu0 = __builtin_fmaf(s0[q], wv[q], mu0);
#pragma unroll 8
  for (int q = 0; q < 64; ++q) mu1 = __builtin_fmaf(s1[q], wv[q], mu1);
  out[tid] = __fmul_rn(__fadd_rn(mu0, mu1), 0.5f);
}

// ---------------------------------------------------------------------------
extern "C" void kernel_launch(void* const* d_in, const int* in_sizes, int n_in,
                              void* d_out, int out_size, void* d_ws, size_t ws_size,
                              hipStream_t stream) {
  (void)in_sizes; (void)n_in; (void)out_size;
  if (ws_size < WS_NEED) return;

  const float* state     = (const float*)d_in[0];
  const float* target    = (const float*)d_in[1];
  const float* W_rec_in  = (const float*)d_in[2];
  const float* b_rec_in  = (const float*)d_in[3];
  const float* W_rec     = (const float*)d_in[4];
  const float* b_rec     = (const float*)d_in[5];
  const float* alpha_rec = (const float*)d_in[6];
  const float* beta_rec  = (const float*)d_in[7];
  const float* W_ff_in   = (const float*)d_in[8];
  const float* b_ff_in   = (const float*)d_in[9];
  const float* alpha_ff  = (const float*)d_in[10];
  const float* beta_ff   = (const float*)d_in[11];
  const float* W_mu_in   = (const float*)d_in[12];
  const float* b_mu_in   = (const float*)d_in[13];
  const float* beta_mu   = (const float*)d_in[14];
  const float* W_mu_out  = (const float*)d_in[15];
  const float* W_lv_in   = (const float*)d_in[16];
  const float* b_lv_in   = (const float*)d_in[17];
  const float* beta_lv   = (const float*)d_in[18];
  const float* W_lv_out  = (const float*)d_in[19];

  char* ws = (char*)d_ws;
  float* XW    = (float*)(ws + XW_OFF);
  float* c3    = (float*)(ws + C3_OFF);
  float* Mem   = (float*)(ws + MEM_OFF);
  u32*   spkb32= (u32*)  (ws + SPKB_OFF);
  float* WT    = (float*)(ws + WT_OFF);
  float* WinT  = (float*)(ws + WINT_OFF);
  u32*   ring32= (u32*)  (ws + RING_OFF);

  hipLaunchKernelGGL(k_prepT, dim3(512), dim3(256), 0, stream,
                     W_rec_in, W_mu_in, W_lv_in, WinT, WT);
  hipLaunchKernelGGL(k_xw, dim3(2048), dim3(256), 0, stream,
                     state, target, WinT, b_rec_in, XW);
  hipLaunchKernelGGL(k_rec, dim3(256), dim3(256), 0, stream,
                     XW, W_rec, W_ff_in,
                     alpha_rec, beta_rec, b_rec,
                     b_ff_in, alpha_ff, beta_ff, ring32, spkb32);
  hipLaunchKernelGGL(k_c3, dim3(2048), dim3(256), 0, stream,
                     spkb32, WT, b_mu_in, b_lv_in, c3);
  hipLaunchKernelGGL(k_scan, dim3(64), dim3(256), 0, stream,
                     c3, beta_mu, beta_lv, Mem);
  hipLaunchKernelGGL(k_out, dim3(2048), dim3(256), 0, stream,
                     Mem, W_mu_out, W_lv_out, (float*)d_out);
}